// Round 12
// baseline (1527.956 us; speedup 1.0000x reference)
//
#include <hip/hip_runtime.h>
#include <hip/hip_bf16.h>
#include <stdint.h>

// CubicModel: out = feats(feats(x)@W0^T + b0)@W1^T + b1
// feats(v) = [v, v_i*v_j (i<=j), v^3], d=512, K=132352
//
// R12: A-fragments computed IN REGISTERS per consumer wave (no LDS for A).
//  Cross-round invariant R3/R6/R9/R10/R11: ~15-18K cyc/step regardless of
//  schedule = the A load->cvt->pack->ds_write->barrier->ds_read chain.
//  A is computed from L2-resident x -> the LDS hop buys nothing.
//  B (HBM W stream) stays in LDS (shared by 4 same-wn waves): 2x16KB dbuf,
//  reg-prefetched W(t+1), ONE __syncthreads/step.
//  512 thr = 8 waves (4m x 2n), BM=256, BN=128, BK=64, acc 4x4/wave.

#define D_IN      512
#define BATCH     512
#define K_TOT     132352
#define QUAD_BASE 512
#define CUBE_BASE 131840
#define BM        256
#define BN        128
#define BK        64

typedef __attribute__((ext_vector_type(8))) __bf16 bf16x8;
typedef __attribute__((ext_vector_type(4))) float  f32x4;

__device__ __forceinline__ bf16x8 pack8(float a0, float a1, float a2, float a3,
                                        float a4, float a5, float a6, float a7) {
    bf16x8 r;
    r[0] = (__bf16)a0; r[1] = (__bf16)a1; r[2] = (__bf16)a2; r[3] = (__bf16)a3;
    r[4] = (__bf16)a4; r[5] = (__bf16)a5; r[6] = (__bf16)a6; r[7] = (__bf16)a7;
    return r;
}

// quad feature index: q -> (i,j), i<=j<512, q = i*(1025-i)/2 + (j-i)
__device__ __forceinline__ void decode_quad(int q, int& oi, int& oj) {
    // disc = 1050625-8q = (1025-2i)^2 at row starts; both < 2^24 -> exact
    float s = sqrtf((float)(1050625 - 8 * q));
    int i = (int)((1025.0f - s) * 0.5f);
    i = i < 0 ? 0 : (i > 511 ? 511 : i);
    while (i < 511 && (i + 1) * (1025 - (i + 1)) / 2 <= q) ++i;
    while (i > 0 && i * (1025 - i) / 2 > q) --i;
    oi = i; oj = i + (q - i * (1025 - i) / 2);
}

// ---------------- fused GEMM, A-in-registers ----------------
// C[m0:m0+256][ldc] += feats(X)[.][K] * W_f32[n0:n0+128][K]^T (+bias ks==0)
__global__ __launch_bounds__(512, 2) void gemm_areg(
    const float* __restrict__ X,
    const float* __restrict__ W,
    float* __restrict__ C, int ldc,
    const float* __restrict__ bias, int split_steps)
{
    __shared__ uint8_t Bsm[2][BN * 128];       // 2 x 16KB bf16, XOR-swizzled

    const int tid  = threadIdx.x;
    const int lane = tid & 63;
    const int wave = tid >> 6;                 // 0..7
    const int wm   = wave >> 1;                // 0..3 : rows wm*64
    const int wn   = wave & 1;                 // 0..1 : cols wn*64
    const int m0   = (blockIdx.x & 1) * BM;
    const int n0   = (blockIdx.x >> 1) * BN;
    const int ks   = blockIdx.y;

    const int kbeg = ks * split_steps * BK;
    const int kend = min(K_TOT, kbeg + split_steps * BK);
    if (kbeg >= kend) return;                  // ks==0 always has work -> bias safe
    const int nt = (kend - kbeg) / BK;

    // ---- B staging ids (all 512 threads): row rb, chunks 2bq,2bq+1 ----
    const int rb = tid >> 2;                   // 0..127
    const int bq = tid & 3;
    const float* const wsrc = W + (size_t)(n0 + rb) * K_TOT + bq * 16;
    const uint32_t bo0 = (uint32_t)rb * 128 + (uint32_t)(((2 * bq)     ^ (rb & 7)) * 16);
    const uint32_t bo1 = (uint32_t)rb * 128 + (uint32_t)(((2 * bq + 1) ^ (rb & 7)) * 16);

    // ---- A addressing: x row pointers per mf (const-indexed -> registers) ----
    const int fr = lane & 15;
    const int h  = lane >> 4;                  // k-chunk 0..3
    const float* xrow0 = X + (size_t)(m0 + wm * 64 +  0 + fr) * D_IN;
    const float* xrow1 = X + (size_t)(m0 + wm * 64 + 16 + fr) * D_IN;
    const float* xrow2 = X + (size_t)(m0 + wm * 64 + 32 + fr) * D_IN;
    const float* xrow3 = X + (size_t)(m0 + wm * 64 + 48 + fr) * D_IN;

    // B fragment read addressing (swizzle: (chunk s*4+h)^(lane&7))
    const uint32_t bbase = (uint32_t)(wn * 64 + fr) * 128;
    const uint32_t cs0 = (uint32_t)((h ^ (lane & 7)) * 16);
    const uint32_t cs1 = cs0 ^ 64u;

    // ---- prologue: stage B(0) ----
    {
        const float* wp = wsrc + kbeg;
        float4 w0 = *(const float4*)(wp);
        float4 w1 = *(const float4*)(wp + 4);
        float4 w2 = *(const float4*)(wp + 8);
        float4 w3 = *(const float4*)(wp + 12);
        *(bf16x8*)(&Bsm[0][bo0]) = pack8(w0.x, w0.y, w0.z, w0.w, w1.x, w1.y, w1.z, w1.w);
        *(bf16x8*)(&Bsm[0][bo1]) = pack8(w2.x, w2.y, w2.z, w2.w, w3.x, w3.y, w3.z, w3.w);
    }
    __syncthreads();

    f32x4 acc[4][4] = {};

    for (int t = 0; t < nt; ++t) {
        const int kw = kbeg + t * BK;
        const uint8_t* const Bb = &Bsm[t & 1][0];

        // ---- classify window (block-uniform) ----
        int mode, iw = 0, jw = 0;
        const int qw = kw - QUAD_BASE;
        if (kw < QUAD_BASE) mode = 0;
        else if (kw >= CUBE_BASE) mode = 1;
        else {
            decode_quad(qw, iw, jw);
            if (jw + 63 <= 511) mode = 2;
            else { int ie, je; decode_quad(qw + 63, ie, je); mode = (ie <= 504) ? 3 : 4; }
        }

        // mode-2 row scales: one scalar load per mf per STEP (shared by s=0,1)
        float xi0 = 0.f, xi1 = 0.f, xi2 = 0.f, xi3 = 0.f;
        if (mode == 2) { xi0 = xrow0[iw]; xi1 = xrow1[iw]; xi2 = xrow2[iw]; xi3 = xrow3[iw]; }

        // ---- issue W(t+1) loads (HBM latency hides under compute) ----
        float4 nw0, nw1, nw2, nw3;
        const bool pre = (t + 1 < nt);
        if (pre) {
            const float* wp = wsrc + kw + BK;
            nw0 = *(const float4*)(wp);
            nw1 = *(const float4*)(wp + 4);
            nw2 = *(const float4*)(wp + 8);
            nw3 = *(const float4*)(wp + 12);
        }

        // ---- compute + MFMA, s = 0,1 ----
        #pragma unroll
        for (int s = 0; s < 2; ++s) {
            const int fk = s * 32 + h * 8;     // k-offset within window
            bf16x8 a[4];

            if (mode == 0) {                   // linear: feats = x
                const int kk = kw + fk;
                {
                    float4 va = *(const float4*)(xrow0 + kk);
                    float4 vb = *(const float4*)(xrow0 + kk + 4);
                    a[0] = pack8(va.x, va.y, va.z, va.w, vb.x, vb.y, vb.z, vb.w);
                }
                {
                    float4 va = *(const float4*)(xrow1 + kk);
                    float4 vb = *(const float4*)(xrow1 + kk + 4);
                    a[1] = pack8(va.x, va.y, va.z, va.w, vb.x, vb.y, vb.z, vb.w);
                }
                {
                    float4 va = *(const float4*)(xrow2 + kk);
                    float4 vb = *(const float4*)(xrow2 + kk + 4);
                    a[2] = pack8(va.x, va.y, va.z, va.w, vb.x, vb.y, vb.z, vb.w);
                }
                {
                    float4 va = *(const float4*)(xrow3 + kk);
                    float4 vb = *(const float4*)(xrow3 + kk + 4);
                    a[3] = pack8(va.x, va.y, va.z, va.w, vb.x, vb.y, vb.z, vb.w);
                }
            } else if (mode == 1) {            // cube
                const int kk = kw - CUBE_BASE + fk;
                #define CUBE_FRAG(idx, XR)                                           \
                {   float4 va = *(const float4*)((XR) + kk);                         \
                    float4 vb = *(const float4*)((XR) + kk + 4);                     \
                    a[idx] = pack8(va.x*va.x*va.x, va.y*va.y*va.y,                   \
                                   va.z*va.z*va.z, va.w*va.w*va.w,                   \
                                   vb.x*vb.x*vb.x, vb.y*vb.y*vb.y,                   \
                                   vb.z*vb.z*vb.z, vb.w*vb.w*vb.w); }
                CUBE_FRAG(0, xrow0) CUBE_FRAG(1, xrow1)
                CUBE_FRAG(2, xrow2) CUBE_FRAG(3, xrow3)
                #undef CUBE_FRAG
            } else if (mode == 2) {            // quad, window inside one triu row
                const int j0 = jw + fk;
                #define Q2_FRAG(idx, XR, XI)                                         \
                {   float4 va = *(const float4*)((XR) + j0);                         \
                    float4 vb = *(const float4*)((XR) + j0 + 4);                     \
                    a[idx] = pack8((XI)*va.x, (XI)*va.y, (XI)*va.z, (XI)*va.w,       \
                                   (XI)*vb.x, (XI)*vb.y, (XI)*vb.z, (XI)*vb.w); }
                Q2_FRAG(0, xrow0, xi0) Q2_FRAG(1, xrow1, xi1)
                Q2_FRAG(2, xrow2, xi2) Q2_FRAG(3, xrow3, xi3)
                #undef Q2_FRAG
            } else if (mode == 3) {            // quad, <=1 row boundary per 8-run
                int i0, j0; decode_quad(qw + fk, i0, j0);
                const int s1   = 512 - j0;     // elems in segment A
                const int off1 = i0 + j0 - 511;// segB index base (row i0+1)
                int xx[8];
                #pragma unroll
                for (int e = 0; e < 8; ++e) xx[e] = (e < s1 ? j0 : off1) + e;
                #define Q3_FRAG(idx, XR)                                             \
                {   const float xa = (XR)[i0];                                       \
                    const float xb = (XR)[i0 + 1];  /* i0<=504 -> in bounds */       \
                    a[idx] = pack8(                                                  \
                        (0 < s1 ? xa : xb) * (XR)[xx[0]], (1 < s1 ? xa : xb) * (XR)[xx[1]], \
                        (2 < s1 ? xa : xb) * (XR)[xx[2]], (3 < s1 ? xa : xb) * (XR)[xx[3]], \
                        (4 < s1 ? xa : xb) * (XR)[xx[4]], (5 < s1 ? xa : xb) * (XR)[xx[5]], \
                        (6 < s1 ? xa : xb) * (XR)[xx[6]], (7 < s1 ? xa : xb) * (XR)[xx[7]]); }
                Q3_FRAG(0, xrow0) Q3_FRAG(1, xrow1)
                Q3_FRAG(2, xrow2) Q3_FRAG(3, xrow3)
                #undef Q3_FRAG
            } else {                           // mode 4: generic tail (1 window/layer)
                int i0, j0; decode_quad(qw + fk, i0, j0);
                int idx[8], si[8];
                { int i = i0, j = j0;
                  #pragma unroll
                  for (int e = 0; e < 8; ++e) {
                      idx[e] = j; si[e] = i;
                      ++j;
                      if (e < 7 && j == 512) { ++i; j = i; }
                  } }
                #define Q4_FRAG(idx_, XR)                                            \
                    a[idx_] = pack8(                                                 \
                        (XR)[si[0]] * (XR)[idx[0]], (XR)[si[1]] * (XR)[idx[1]],      \
                        (XR)[si[2]] * (XR)[idx[2]], (XR)[si[3]] * (XR)[idx[3]],      \
                        (XR)[si[4]] * (XR)[idx[4]], (XR)[si[5]] * (XR)[idx[5]],      \
                        (XR)[si[6]] * (XR)[idx[6]], (XR)[si[7]] * (XR)[idx[7]]);
                Q4_FRAG(0, xrow0) Q4_FRAG(1, xrow1)
                Q4_FRAG(2, xrow2) Q4_FRAG(3, xrow3)
                #undef Q4_FRAG
            }

            // ---- MFMA: 4 B-frags x 4 A-frags ----
            const uint32_t cs = s ? cs1 : cs0;
            __builtin_amdgcn_s_setprio(1);
            #pragma unroll
            for (int nf = 0; nf < 4; ++nf) {
                bf16x8 b = *(const bf16x8*)(Bb + bbase + nf * 2048u + cs);
                #pragma unroll
                for (int mf = 0; mf < 4; ++mf)
                    acc[mf][nf] = __builtin_amdgcn_mfma_f32_16x16x32_bf16(a[mf], b, acc[mf][nf], 0, 0, 0);
            }
            __builtin_amdgcn_s_setprio(0);
        }

        // ---- pack + write B(t+1) into the other buffer ----
        if (pre) {
            uint8_t* const Bn = &Bsm[(t + 1) & 1][0];
            *(bf16x8*)(Bn + bo0) = pack8(nw0.x, nw0.y, nw0.z, nw0.w,
                                         nw1.x, nw1.y, nw1.z, nw1.w);
            *(bf16x8*)(Bn + bo1) = pack8(nw2.x, nw2.y, nw2.z, nw2.w,
                                         nw3.x, nw3.y, nw3.z, nw3.w);
        }
        __syncthreads();
    }

    // epilogue: C/D layout col=lane&15, row=(lane>>4)*4+reg  [m89-verified]
    const bool dob = (ks == 0);
    const int rbase = m0 + wm * 64 + (lane >> 4) * 4;
    const int cbase = n0 + wn * 64 + (lane & 15);
    #pragma unroll
    for (int nf = 0; nf < 4; ++nf) {
        const int col = cbase + nf * 16;
        const float bv = dob ? bias[col] : 0.0f;
        #pragma unroll
        for (int mf = 0; mf < 4; ++mf) {
            const int row = rbase + mf * 16;
            #pragma unroll
            for (int r = 0; r < 4; ++r)
                unsafeAtomicAdd(&C[(size_t)(row + r) * ldc + col], acc[mf][nf][r] + bv);
        }
    }
}

// ---------------- host ----------------
extern "C" void kernel_launch(void* const* d_in, const int* in_sizes, int n_in,
                              void* d_out, int out_size, void* d_ws, size_t ws_size,
                              hipStream_t stream)
{
    const float* x  = (const float*)d_in[0];
    const float* W0 = (const float*)d_in[1];
    const float* b0 = (const float*)d_in[2];
    const float* W1 = (const float*)d_in[3];
    const float* b1 = (const float*)d_in[4];
    float* out = (float*)d_out;

    float* hbuf = (float*)d_ws;                        // [512][512]
    const size_t hbytes = (size_t)BATCH * 512 * 4;

    hipMemsetAsync(hbuf, 0, hbytes, stream);
    hipMemsetAsync(out, 0, (size_t)out_size * 4, stream);

    const int TS = K_TOT / BK;                         // 2068 K-steps total

    // layer 0: 2 m-blocks x 4 n-blocks x 32 ks = 256 blocks (1/CU), nt<=65
    {
        const int ss = 65;
        const int gy = (TS + ss - 1) / ss;             // 32
        gemm_areg<<<dim3(8, gy), 512, 0, stream>>>(
            x, W0, hbuf, 512, b0, ss);
    }
    // layer 1: 2 m-blocks x 2 n-blocks x 63 ks = 252 blocks, nt<=33
    {
        const int ss = 33;
        const int gy = (TS + ss - 1) / ss;             // 63
        gemm_areg<<<dim3(4, gy), 512, 0, stream>>>(
            hbuf, W1, out, 256, b1, ss);
    }
}

// Round 13
// 700.059 us; speedup vs baseline: 2.1826x; 2.1826x over previous
//
#include <hip/hip_runtime.h>
#include <hip/hip_bf16.h>
#include <stdint.h>

// CubicModel: out = feats(feats(x)@W0^T + b0)@W1^T + b1
// feats(v) = [v, v_i*v_j (i<=j), v^3], d=512, K=132352
//
// R13 = R6 (353us, best) + ONE change: divergence-free stage_A.
//  R6 ran decode_quad per-thread every step (divergent while-fixups) and
//  double-executed both quad paths on row-boundary windows (~25%).
//  Now: block-uniform window classification; mode2 (one-row window, ~75%)
//  has zero per-thread decode; mode3 (boundary) is branchless 2-segment
//  select with named scalars (no arrays -> no scratch risk); mode4 = rare
//  tail. Everything else byte-identical to R6.
//  (R12 post-mortem: A-frags-from-global = fragment-order gather, 35K
//   cyc/step; LDS staging is what makes the loads coalesced. Keep it.)

#define D_IN      512
#define BATCH     512
#define K_TOT     132352
#define QUAD_BASE 512
#define CUBE_BASE 131840
#define BN        128
#define BK        64          // LDS row = 128 B

typedef __attribute__((ext_vector_type(8))) __bf16 bf16x8;
typedef __attribute__((ext_vector_type(4))) float  f32x4;

__device__ __forceinline__ bf16x8 pack8(float a0, float a1, float a2, float a3,
                                        float a4, float a5, float a6, float a7) {
    bf16x8 r;
    r[0] = (__bf16)a0; r[1] = (__bf16)a1; r[2] = (__bf16)a2; r[3] = (__bf16)a3;
    r[4] = (__bf16)a4; r[5] = (__bf16)a5; r[6] = (__bf16)a6; r[7] = (__bf16)a7;
    return r;
}

// quad feature index: q -> (i,j), i<=j<512, q = i*(1025-i)/2 + (j-i)
__device__ __forceinline__ void decode_quad(int q, int& oi, int& oj) {
    // disc = 1050625-8q = (1025-2i)^2 at row starts; both < 2^24 -> exact
    float s = sqrtf((float)(1050625 - 8 * q));
    int i = (int)((1025.0f - s) * 0.5f);
    i = i < 0 ? 0 : (i > 511 ? 511 : i);
    while (i < 511 && (i + 1) * (1025 - (i + 1)) / 2 <= q) ++i;
    while (i > 0 && i * (1025 - i) / 2 > q) --i;
    oi = i; oj = i + (q - i * (1025 - i) / 2);
}

// stage feats for window [kw,kw+64): thread -> chunk c=tid&7 of rows
// {r0, r0+128, r0+256, r0+384}, r0=tid>>3. Swizzled write offset is
// p-invariant (row&7 == r0&7). Block-uniform mode classification.
__device__ __forceinline__ void stage_A(const float* __restrict__ X,
                                        uint8_t* __restrict__ Ab,
                                        int kw, int tid) {
    const int c  = tid & 7;
    const int r0 = tid >> 3;
    const int k  = kw + c * 8;
    uint8_t* const wp0 = Ab + (size_t)r0 * 128 + (uint32_t)((c ^ (r0 & 7)) * 16);
    const float* const xr = X + (size_t)r0 * D_IN;

    if (kw < QUAD_BASE) {                      // linear window
        #pragma unroll 2
        for (int p = 0; p < 4; ++p) {
            const float* row = xr + (size_t)p * (128 * D_IN);
            float4 a = *(const float4*)(row + k);
            float4 b = *(const float4*)(row + k + 4);
            *(bf16x8*)(wp0 + p * 16384) = pack8(a.x, a.y, a.z, a.w, b.x, b.y, b.z, b.w);
        }
    } else if (kw >= CUBE_BASE) {              // cube window
        const int tt = k - CUBE_BASE;
        #pragma unroll 2
        for (int p = 0; p < 4; ++p) {
            const float* row = xr + (size_t)p * (128 * D_IN);
            float4 a = *(const float4*)(row + tt);
            float4 b = *(const float4*)(row + tt + 4);
            *(bf16x8*)(wp0 + p * 16384) = pack8(
                a.x * a.x * a.x, a.y * a.y * a.y, a.z * a.z * a.z, a.w * a.w * a.w,
                b.x * b.x * b.x, b.y * b.y * b.y, b.z * b.z * b.z, b.w * b.w * b.w);
        }
    } else {                                   // quad window, block-uniform class
        const int qw = kw - QUAD_BASE;
        int iw, jw; decode_quad(qw, iw, jw);
        if (jw + 63 <= 511) {                  // mode 2: window inside row iw
            const int j0 = jw + c * 8;         // no per-thread decode
            #pragma unroll 2
            for (int p = 0; p < 4; ++p) {
                const float* row = xr + (size_t)p * (128 * D_IN);
                const float xi = row[iw];
                float4 a = *(const float4*)(row + j0);
                float4 b = *(const float4*)(row + j0 + 4);
                *(bf16x8*)(wp0 + p * 16384) = pack8(
                    xi * a.x, xi * a.y, xi * a.z, xi * a.w,
                    xi * b.x, xi * b.y, xi * b.z, xi * b.w);
            }
        } else {
            int ie, je; decode_quad(qw + 63, ie, je);
            if (ie <= 504) {                   // mode 3: rows in window len>=8
                                               // -> <=1 boundary per 8-run
                int i0, j0; decode_quad(qw + c * 8, i0, j0);
                const int s1   = 512 - j0;     // elems in segment A
                const int off1 = i0 + j0 - 511;// segB index base (row i0+1)
                const int x0 = (0 < s1 ? j0 : off1) + 0;
                const int x1 = (1 < s1 ? j0 : off1) + 1;
                const int x2 = (2 < s1 ? j0 : off1) + 2;
                const int x3 = (3 < s1 ? j0 : off1) + 3;
                const int x4 = (4 < s1 ? j0 : off1) + 4;
                const int x5 = (5 < s1 ? j0 : off1) + 5;
                const int x6 = (6 < s1 ? j0 : off1) + 6;
                const int x7 = (7 < s1 ? j0 : off1) + 7;
                #pragma unroll 2
                for (int p = 0; p < 4; ++p) {
                    const float* row = xr + (size_t)p * (128 * D_IN);
                    const float xa = row[i0];
                    const float xb = row[i0 + 1];      // i0<=504 -> in bounds
                    *(bf16x8*)(wp0 + p * 16384) = pack8(
                        (0 < s1 ? xa : xb) * row[x0], (1 < s1 ? xa : xb) * row[x1],
                        (2 < s1 ? xa : xb) * row[x2], (3 < s1 ? xa : xb) * row[x3],
                        (4 < s1 ? xa : xb) * row[x4], (5 < s1 ? xa : xb) * row[x5],
                        (6 < s1 ? xa : xb) * row[x6], (7 < s1 ? xa : xb) * row[x7]);
                }
            } else {                           // mode 4: tail (~2 windows/layer)
                int i0, j0; decode_quad(qw + c * 8, i0, j0);
                #pragma unroll 1
                for (int p = 0; p < 4; ++p) {
                    const float* row = xr + (size_t)p * (128 * D_IN);
                    int i = i0, j = j0;
                    float xi = row[i];
                    float v0, v1, v2, v3, v4, v5, v6, v7;
                    v0 = xi * row[j]; ++j; if (j == 512) { ++i; j = i; xi = row[i]; }
                    v1 = xi * row[j]; ++j; if (j == 512) { ++i; j = i; xi = row[i]; }
                    v2 = xi * row[j]; ++j; if (j == 512) { ++i; j = i; xi = row[i]; }
                    v3 = xi * row[j]; ++j; if (j == 512) { ++i; j = i; xi = row[i]; }
                    v4 = xi * row[j]; ++j; if (j == 512) { ++i; j = i; xi = row[i]; }
                    v5 = xi * row[j]; ++j; if (j == 512) { ++i; j = i; xi = row[i]; }
                    v6 = xi * row[j]; ++j; if (j == 512) { ++i; j = i; xi = row[i]; }
                    v7 = xi * row[j];
                    *(bf16x8*)(wp0 + p * 16384) = pack8(v0, v1, v2, v3, v4, v5, v6, v7);
                }
            }
        }
    }
}

// ---------------- fused GEMM ----------------
// C[512][ldc] += feats(X)[512][K] * W_f32[n][K]^T (+bias by ks==0 blocks)
// 1024 thr = 16 waves (8m x 2n), wave tile 64x64, mfma 16x16x32, acc 4x4.
// LDS: A0,A1 64KB each; B0,B1 16KB each = 160KB dynamic.
__global__ __launch_bounds__(1024, 1) void gemm_fused(
    const float* __restrict__ X,
    const float* __restrict__ W,
    float* __restrict__ C, int ldc,
    const float* __restrict__ bias, int split_steps)
{
    extern __shared__ uint8_t smem[];
    const int tid  = threadIdx.x;
    const int lane = tid & 63;
    const int wave = tid >> 6;
    const int wm   = wave >> 1;                // 0..7
    const int wn   = wave & 1;                 // 0..1
    const int n0   = blockIdx.x * BN;
    const int ks   = blockIdx.y;

    const int kbeg = ks * split_steps * BK;
    const int kend = min(K_TOT, kbeg + split_steps * BK);
    if (kbeg >= kend) return;                  // ks==0 always has work -> bias safe
    const int nt = (kend - kbeg) / BK;

    // B staging: thread -> (row=tid>>3, chunk=tid&7)
    const int brow   = tid >> 3;
    const int bchunk = tid & 7;
    const float* const wsrc = W + (size_t)(n0 + brow) * K_TOT + bchunk * 8;
    const uint32_t boff = (uint32_t)brow * 128 + (uint32_t)((bchunk ^ (brow & 7)) * 16);

    // ---- prologue: tile 0 into buf0 ----
    {
        float4 w0 = *(const float4*)(wsrc + kbeg);
        float4 w1 = *(const float4*)(wsrc + kbeg + 4);
        stage_A(X, smem, kbeg, tid);
        *(bf16x8*)(smem + 131072 + boff) =
            pack8(w0.x, w0.y, w0.z, w0.w, w1.x, w1.y, w1.z, w1.w);
    }
    __syncthreads();

    f32x4 acc[4][4] = {};
    const int fr = lane & 15;
    const int h  = lane >> 4;
    // frag addressing, hoisted: row&7 == lane&7 for every fragment ->
    // shared swizzled chunk offsets cs0 (s=0), cs1 = cs0^64 (s=1).
    uint32_t aoff[4], boffr[4];
    #pragma unroll
    for (int i = 0; i < 4; ++i) {
        aoff[i]  = (uint32_t)(wm * 64 + i * 16 + fr) * 128;
        boffr[i] = (uint32_t)(wn * 64 + i * 16 + fr) * 128;
    }
    const uint32_t cs0 = (uint32_t)((h ^ (lane & 7)) * 16);
    const uint32_t cs1 = cs0 ^ 64u;

    for (int t = 0; t < nt; ++t) {
        const uint32_t cur = (uint32_t)(t & 1);
        const uint8_t* const Ab = smem + cur * 65536u;
        const uint8_t* const Bb = smem + 131072u + cur * 16384u;
        const bool pre = (t + 1 < nt);
        const int kkn = kbeg + (t + 1) * BK;

        // issue next W loads early (latency covered by MFMA phase)
        float4 nw0, nw1;
        if (pre) {
            nw0 = *(const float4*)(wsrc + kkn);
            nw1 = *(const float4*)(wsrc + kkn + 4);
        }

        // ---- MFMA phase on tile t ----
        __builtin_amdgcn_s_setprio(1);
        #pragma unroll
        for (int s = 0; s < 2; ++s) {
            const uint32_t cs = s ? cs1 : cs0;
            bf16x8 a[4];
            #pragma unroll
            for (int mf = 0; mf < 4; ++mf)
                a[mf] = *(const bf16x8*)(Ab + aoff[mf] + cs);
            #pragma unroll
            for (int nf = 0; nf < 4; ++nf) {
                bf16x8 b = *(const bf16x8*)(Bb + boffr[nf] + cs);
                #pragma unroll
                for (int mf = 0; mf < 4; ++mf)
                    acc[mf][nf] = __builtin_amdgcn_mfma_f32_16x16x32_bf16(a[mf], b, acc[mf][nf], 0, 0, 0);
            }
        }
        __builtin_amdgcn_s_setprio(0);

        // ---- stage tile t+1 (other buffers; last read in iter t-1, ordered
        // by that iter's barrier) ----
        if (pre) {
            stage_A(X, smem + (cur ^ 1u) * 65536u, kkn, tid);
            *(bf16x8*)(smem + 131072u + (cur ^ 1u) * 16384u + boff) =
                pack8(nw0.x, nw0.y, nw0.z, nw0.w, nw1.x, nw1.y, nw1.z, nw1.w);
        }
        __syncthreads();
    }

    // epilogue: C/D layout col=lane&15, row=(lane>>4)*4+reg  [m89-verified]
    const bool dob = (ks == 0);
    const int rbase = wm * 64 + (lane >> 4) * 4;
    const int cbase = n0 + wn * 64 + (lane & 15);
    #pragma unroll
    for (int nf = 0; nf < 4; ++nf) {
        const int col = cbase + nf * 16;
        const float bv = dob ? bias[col] : 0.0f;
        #pragma unroll
        for (int mf = 0; mf < 4; ++mf) {
            const int row = rbase + mf * 16;
            #pragma unroll
            for (int r = 0; r < 4; ++r)
                unsafeAtomicAdd(&C[(size_t)(row + r) * ldc + col], acc[mf][nf][r] + bv);
        }
    }
}

// ---------------- host ----------------
extern "C" void kernel_launch(void* const* d_in, const int* in_sizes, int n_in,
                              void* d_out, int out_size, void* d_ws, size_t ws_size,
                              hipStream_t stream)
{
    const float* x  = (const float*)d_in[0];
    const float* W0 = (const float*)d_in[1];
    const float* b0 = (const float*)d_in[2];
    const float* W1 = (const float*)d_in[3];
    const float* b1 = (const float*)d_in[4];
    float* out = (float*)d_out;

    float* hbuf = (float*)d_ws;                        // [512][512]
    const size_t hbytes = (size_t)BATCH * 512 * 4;

    static int lds_set = 0;
    if (!lds_set) {    // host-side, idempotent, outside stream -> capture-safe
        hipFuncSetAttribute((const void*)gemm_fused,
                            hipFuncAttributeMaxDynamicSharedMemorySize, 163840);
        lds_set = 1;
    }

    hipMemsetAsync(hbuf, 0, hbytes, stream);
    hipMemsetAsync(out, 0, (size_t)out_size * 4, stream);

    const int TS = K_TOT / BK;                         // 2068 K-steps total

    // layer 0: h = feats(x) @ W0^T + b0     grid (4, 63) = 252 blocks
    {
        const int ss = 33;
        const int gy = (TS + ss - 1) / ss;             // 63
        gemm_fused<<<dim3(512 / BN, gy), 1024, 163840, stream>>>(
            x, W0, hbuf, 512, b0, ss);
    }
    // layer 1: out = feats(h) @ W1^T + b1   grid (2, 122) = 244 blocks
    {
        const int ss = 17;
        const int gy = (TS + ss - 1) / ss;             // 122
        gemm_fused<<<dim3(256 / BN, gy), 1024, 163840, stream>>>(
            hbuf, W1, out, 256, b1, ss);
    }
}

// Round 14
// 394.058 us; speedup vs baseline: 3.8775x; 1.7765x over previous
//
#include <hip/hip_runtime.h>
#include <hip/hip_bf16.h>
#include <stdint.h>

// CubicModel: out = feats(feats(x)@W0^T + b0)@W1^T + b1
// feats(v) = [v, v_i*v_j (i<=j), v^3], d=512, K=132352
//
// R14 = R6 (353us, best) + ONE surgical change: block-uniform mode-2 fast
//  path for quad windows fully inside one triu row (~75% of quad windows:
//  zero per-thread decode). ALL other windows take R6's per-thread path
//  VERBATIM (float4 fast / serial walk).
//  R13 post-mortem: its mode-3 "branchless" path was 40 scalar gather
//  loads/thread -> ~20K extra cyc on 25% of steps (gather through VMEM is
//  5-10x a float4 stream). Keep R13's win, revert its loss.

#define D_IN      512
#define BATCH     512
#define K_TOT     132352
#define QUAD_BASE 512
#define CUBE_BASE 131840
#define BN        128
#define BK        64          // LDS row = 128 B

typedef __attribute__((ext_vector_type(8))) __bf16 bf16x8;
typedef __attribute__((ext_vector_type(4))) float  f32x4;

__device__ __forceinline__ bf16x8 pack8(float a0, float a1, float a2, float a3,
                                        float a4, float a5, float a6, float a7) {
    bf16x8 r;
    r[0] = (__bf16)a0; r[1] = (__bf16)a1; r[2] = (__bf16)a2; r[3] = (__bf16)a3;
    r[4] = (__bf16)a4; r[5] = (__bf16)a5; r[6] = (__bf16)a6; r[7] = (__bf16)a7;
    return r;
}

// quad feature index: q -> (i,j), i<=j<512, q = i*(1025-i)/2 + (j-i)
__device__ __forceinline__ void decode_quad(int q, int& oi, int& oj) {
    // disc = 1050625-8q = (1025-2i)^2 at row starts; both < 2^24 -> exact
    float s = sqrtf((float)(1050625 - 8 * q));
    int i = (int)((1025.0f - s) * 0.5f);
    i = i < 0 ? 0 : (i > 511 ? 511 : i);
    while (i < 511 && (i + 1) * (1025 - (i + 1)) / 2 <= q) ++i;
    while (i > 0 && i * (1025 - i) / 2 > q) --i;
    oi = i; oj = i + (q - i * (1025 - i) / 2);
}

// stage feats for window [kw,kw+64): thread -> chunk c=tid&7 of rows
// {r0, r0+128, r0+256, r0+384}. Swizzled write offset is p-invariant.
__device__ __forceinline__ void stage_A(const float* __restrict__ X,
                                        uint8_t* __restrict__ Ab,
                                        int kw, int tid) {
    const int c  = tid & 7;
    const int r0 = tid >> 3;
    const int k  = kw + c * 8;
    uint8_t* const wp0 = Ab + (size_t)r0 * 128 + (uint32_t)((c ^ (r0 & 7)) * 16);
    const float* const xrow = X + (size_t)r0 * D_IN;

    if (kw < QUAD_BASE) {                      // linear window
        #pragma unroll 2
        for (int p = 0; p < 4; ++p) {
            const float* row = xrow + (size_t)p * (128 * D_IN);
            float4 a = *(const float4*)(row + k);
            float4 b = *(const float4*)(row + k + 4);
            *(bf16x8*)(wp0 + p * 16384) = pack8(a.x, a.y, a.z, a.w, b.x, b.y, b.z, b.w);
        }
    } else if (kw >= CUBE_BASE) {              // cube window
        const int tt = k - CUBE_BASE;
        #pragma unroll 2
        for (int p = 0; p < 4; ++p) {
            const float* row = xrow + (size_t)p * (128 * D_IN);
            float4 a = *(const float4*)(row + tt);
            float4 b = *(const float4*)(row + tt + 4);
            *(bf16x8*)(wp0 + p * 16384) = pack8(
                a.x * a.x * a.x, a.y * a.y * a.y, a.z * a.z * a.z, a.w * a.w * a.w,
                b.x * b.x * b.x, b.y * b.y * b.y, b.z * b.z * b.z, b.w * b.w * b.w);
        }
    } else {                                   // quad window
        const int qw = kw - QUAD_BASE;
        int iw, jw; decode_quad(qw, iw, jw);   // block-uniform
        if (jw + 63 <= 511) {
            // mode 2 (~75% of quad windows): whole window inside triu row iw
            // -> zero per-thread decode, pure float4 stream
            const int j0 = jw + c * 8;
            #pragma unroll 2
            for (int p = 0; p < 4; ++p) {
                const float* row = xrow + (size_t)p * (128 * D_IN);
                const float xi = row[iw];
                float4 a = *(const float4*)(row + j0);
                float4 b = *(const float4*)(row + j0 + 4);
                *(bf16x8*)(wp0 + p * 16384) = pack8(
                    xi * a.x, xi * a.y, xi * a.z, xi * a.w,
                    xi * b.x, xi * b.y, xi * b.z, xi * b.w);
            }
        } else {
            // boundary window: R6's per-thread path VERBATIM (benched 353us)
            int i0, j0; decode_quad(qw + c * 8, i0, j0);
            if (j0 <= 504) {                   // 8-run stays inside triu row i0
                #pragma unroll 2
                for (int p = 0; p < 4; ++p) {
                    const float* row = xrow + (size_t)p * (128 * D_IN);
                    const float xi = row[i0];
                    float4 a = *(const float4*)(row + j0);
                    float4 b = *(const float4*)(row + j0 + 4);
                    *(bf16x8*)(wp0 + p * 16384) = pack8(
                        xi * a.x, xi * a.y, xi * a.z, xi * a.w,
                        xi * b.x, xi * b.y, xi * b.z, xi * b.w);
                }
            } else {                           // wraps one or more row ends
                #pragma unroll 2
                for (int p = 0; p < 4; ++p) {
                    const float* row = xrow + (size_t)p * (128 * D_IN);
                    int i = i0, j = j0;
                    float xi = row[i];
                    float v[8];
                    #pragma unroll
                    for (int e = 0; e < 8; ++e) {
                        v[e] = xi * row[j];
                        ++j;
                        if (j == 512) { ++i; j = i; xi = row[i]; }
                    }
                    *(bf16x8*)(wp0 + p * 16384) = pack8(v[0], v[1], v[2], v[3],
                                                        v[4], v[5], v[6], v[7]);
                }
            }
        }
    }
}

// ---------------- fused GEMM ----------------
// C[512][ldc] += feats(X)[512][K] * W_f32[n][K]^T (+bias by ks==0 blocks)
// 1024 thr = 16 waves (8m x 2n), wave tile 64x64, mfma 16x16x32, acc 4x4.
// LDS: A0,A1 64KB each; B0,B1 16KB each = 160KB dynamic.
__global__ __launch_bounds__(1024, 1) void gemm_fused(
    const float* __restrict__ X,
    const float* __restrict__ W,
    float* __restrict__ C, int ldc,
    const float* __restrict__ bias, int split_steps)
{
    extern __shared__ uint8_t smem[];
    const int tid  = threadIdx.x;
    const int lane = tid & 63;
    const int wave = tid >> 6;
    const int wm   = wave >> 1;                // 0..7
    const int wn   = wave & 1;                 // 0..1
    const int n0   = blockIdx.x * BN;
    const int ks   = blockIdx.y;

    const int kbeg = ks * split_steps * BK;
    const int kend = min(K_TOT, kbeg + split_steps * BK);
    if (kbeg >= kend) return;                  // ks==0 always has work -> bias safe
    const int nt = (kend - kbeg) / BK;

    // B staging: thread -> (row=tid>>3, chunk=tid&7)
    const int brow   = tid >> 3;
    const int bchunk = tid & 7;
    const float* const wsrc = W + (size_t)(n0 + brow) * K_TOT + bchunk * 8;
    const uint32_t boff = (uint32_t)brow * 128 + (uint32_t)((bchunk ^ (brow & 7)) * 16);

    // ---- prologue: tile 0 into buf0 ----
    {
        float4 w0 = *(const float4*)(wsrc + kbeg);
        float4 w1 = *(const float4*)(wsrc + kbeg + 4);
        stage_A(X, smem, kbeg, tid);
        *(bf16x8*)(smem + 131072 + boff) =
            pack8(w0.x, w0.y, w0.z, w0.w, w1.x, w1.y, w1.z, w1.w);
    }
    __syncthreads();

    f32x4 acc[4][4] = {};
    const int fr = lane & 15;
    const int h  = lane >> 4;
    // frag addressing, hoisted: row&7 == lane&7 for every fragment ->
    // shared swizzled chunk offsets cs0 (s=0), cs1 = cs0^64 (s=1).
    uint32_t aoff[4], boffr[4];
    #pragma unroll
    for (int i = 0; i < 4; ++i) {
        aoff[i]  = (uint32_t)(wm * 64 + i * 16 + fr) * 128;
        boffr[i] = (uint32_t)(wn * 64 + i * 16 + fr) * 128;
    }
    const uint32_t cs0 = (uint32_t)((h ^ (lane & 7)) * 16);
    const uint32_t cs1 = cs0 ^ 64u;

    for (int t = 0; t < nt; ++t) {
        const uint32_t cur = (uint32_t)(t & 1);
        const uint8_t* const Ab = smem + cur * 65536u;
        const uint8_t* const Bb = smem + 131072u + cur * 16384u;
        const bool pre = (t + 1 < nt);
        const int kkn = kbeg + (t + 1) * BK;

        // issue next W loads early (latency covered by MFMA phase)
        float4 nw0, nw1;
        if (pre) {
            nw0 = *(const float4*)(wsrc + kkn);
            nw1 = *(const float4*)(wsrc + kkn + 4);
        }

        // ---- MFMA phase on tile t ----
        __builtin_amdgcn_s_setprio(1);
        #pragma unroll
        for (int s = 0; s < 2; ++s) {
            const uint32_t cs = s ? cs1 : cs0;
            bf16x8 a[4];
            #pragma unroll
            for (int mf = 0; mf < 4; ++mf)
                a[mf] = *(const bf16x8*)(Ab + aoff[mf] + cs);
            #pragma unroll
            for (int nf = 0; nf < 4; ++nf) {
                bf16x8 b = *(const bf16x8*)(Bb + boffr[nf] + cs);
                #pragma unroll
                for (int mf = 0; mf < 4; ++mf)
                    acc[mf][nf] = __builtin_amdgcn_mfma_f32_16x16x32_bf16(a[mf], b, acc[mf][nf], 0, 0, 0);
            }
        }
        __builtin_amdgcn_s_setprio(0);

        // ---- stage tile t+1 (other buffers; last read in iter t-1, ordered
        // by that iter's barrier) ----
        if (pre) {
            stage_A(X, smem + (cur ^ 1u) * 65536u, kkn, tid);
            *(bf16x8*)(smem + 131072u + (cur ^ 1u) * 16384u + boff) =
                pack8(nw0.x, nw0.y, nw0.z, nw0.w, nw1.x, nw1.y, nw1.z, nw1.w);
        }
        __syncthreads();
    }

    // epilogue: C/D layout col=lane&15, row=(lane>>4)*4+reg  [m89-verified]
    const bool dob = (ks == 0);
    const int rbase = wm * 64 + (lane >> 4) * 4;
    const int cbase = n0 + wn * 64 + (lane & 15);
    #pragma unroll
    for (int nf = 0; nf < 4; ++nf) {
        const int col = cbase + nf * 16;
        const float bv = dob ? bias[col] : 0.0f;
        #pragma unroll
        for (int mf = 0; mf < 4; ++mf) {
            const int row = rbase + mf * 16;
            #pragma unroll
            for (int r = 0; r < 4; ++r)
                unsafeAtomicAdd(&C[(size_t)(row + r) * ldc + col], acc[mf][nf][r] + bv);
        }
    }
}

// ---------------- host ----------------
extern "C" void kernel_launch(void* const* d_in, const int* in_sizes, int n_in,
                              void* d_out, int out_size, void* d_ws, size_t ws_size,
                              hipStream_t stream)
{
    const float* x  = (const float*)d_in[0];
    const float* W0 = (const float*)d_in[1];
    const float* b0 = (const float*)d_in[2];
    const float* W1 = (const float*)d_in[3];
    const float* b1 = (const float*)d_in[4];
    float* out = (float*)d_out;

    float* hbuf = (float*)d_ws;                        // [512][512]
    const size_t hbytes = (size_t)BATCH * 512 * 4;

    static int lds_set = 0;
    if (!lds_set) {    // host-side, idempotent, outside stream -> capture-safe
        hipFuncSetAttribute((const void*)gemm_fused,
                            hipFuncAttributeMaxDynamicSharedMemorySize, 163840);
        lds_set = 1;
    }

    hipMemsetAsync(hbuf, 0, hbytes, stream);
    hipMemsetAsync(out, 0, (size_t)out_size * 4, stream);

    const int TS = K_TOT / BK;                         // 2068 K-steps total

    // layer 0: h = feats(x) @ W0^T + b0     grid (4, 63) = 252 blocks
    {
        const int ss = 33;
        const int gy = (TS + ss - 1) / ss;             // 63
        gemm_fused<<<dim3(512 / BN, gy), 1024, 163840, stream>>>(
            x, W0, hbuf, 512, b0, ss);
    }
    // layer 1: out = feats(h) @ W1^T + b1   grid (2, 122) = 244 blocks
    {
        const int ss = 17;
        const int gy = (TS + ss - 1) / ss;             // 122
        gemm_fused<<<dim3(256 / BN, gy), 1024, 163840, stream>>>(
            hbuf, W1, out, 256, b1, ss);
    }
}